// Round 1
// baseline (78.807 us; speedup 1.0000x reference)
//
#include <hip/hip_runtime.h>
#include <hip/hip_bf16.h>

// B=32, N=64, D=128, H=256
#define BB 32
#define NN 64
#define DD 128
#define HH 256

typedef __attribute__((ext_vector_type(8))) short short8;
typedef __attribute__((ext_vector_type(4))) float f32x4;

static __device__ __forceinline__ unsigned short f2bf(float f) {
    union { float f; unsigned u; } v; v.f = f;
    unsigned r = v.u + 0x7FFF + ((v.u >> 16) & 1);
    return (unsigned short)(r >> 16);
}

// ---------------------------------------------------------------------------
// Prep: blocks 0..127  : L/R = objects @ gW1(top/bottom)   (16 rows each)
//       blocks 128..143: transpose-convert gW2 -> W2T bf16 (64x64 tiles)
//       block  144     : zero S
// ---------------------------------------------------------------------------
__global__ __launch_bounds__(256) void rn_prep(
    const float* __restrict__ obj, const float* __restrict__ gW1,
    const float* __restrict__ gW2,
    float* __restrict__ L, float* __restrict__ Rm,
    unsigned short* __restrict__ W2T, float* __restrict__ S)
{
    __shared__ float so[16 * 128];
    __shared__ float tt[64 * 65];
    const int blk = blockIdx.x;
    const int t = threadIdx.x;

    if (blk < 128) {
        const int r0 = blk * 16;
        for (int it = 0; it < 8; ++it) {
            int idx = it * 256 + t;
            so[idx] = obj[r0 * 128 + idx];
        }
        __syncthreads();
        float accL[16], accR[16];
        #pragma unroll
        for (int r = 0; r < 16; ++r) { accL[r] = 0.f; accR[r] = 0.f; }
        for (int k = 0; k < 128; ++k) {
            float wL = gW1[k * 256 + t];
            float wR = gW1[(128 + k) * 256 + t];
            #pragma unroll
            for (int r = 0; r < 16; ++r) {
                float o = so[r * 128 + k];
                accL[r] += o * wL;
                accR[r] += o * wR;
            }
        }
        #pragma unroll
        for (int r = 0; r < 16; ++r) {
            L [(r0 + r) * 256 + t] = accL[r];
            Rm[(r0 + r) * 256 + t] = accR[r];
        }
    } else if (blk < 144) {
        const int tb = blk - 128;
        const int k0 = (tb >> 2) * 64, c0 = (tb & 3) * 64;
        for (int it = 0; it < 16; ++it) {
            int idx = it * 256 + t;
            int rr = idx >> 6, cc = idx & 63;
            tt[rr * 65 + cc] = gW2[(k0 + rr) * 256 + c0 + cc];
        }
        __syncthreads();
        for (int it = 0; it < 16; ++it) {
            int idx = it * 256 + t;
            int cr = idx >> 6, kk = idx & 63;
            W2T[(c0 + cr) * 256 + (k0 + kk)] = f2bf(tt[kk * 65 + cr]);
        }
    } else {
        for (int it = 0; it < 32; ++it) S[it * 256 + t] = 0.f;
    }
}

// ---------------------------------------------------------------------------
// Main: one block per (b, i). 64 j-rows x 256 cols of h2 = relu(h1@W2+b2),
// column-summed (excluding j==i) into S[b,:] via atomicAdd.
// h1[j][c] = relu(L[b,i][c] + gb1[c] + R[b,j][c]) built in LDS (bf16,
// XOR-swizzled rows, stride 512B). W2T staged per-64-K chunk (swizzled,
// stride 128B). mfma_f32_16x16x32_bf16, 4 waves x (64 rows x 64 cols).
// ---------------------------------------------------------------------------
__global__ __launch_bounds__(256) void rn_main(
    const float* __restrict__ L, const float* __restrict__ Rm,
    const unsigned short* __restrict__ W2T,
    const float* __restrict__ gb1, const float* __restrict__ gb2,
    float* __restrict__ S)
{
    __shared__ __attribute__((aligned(16))) unsigned short h1s[64 * 256];  // 32 KB
    __shared__ __attribute__((aligned(16))) unsigned short w2s[256 * 64];  // 32 KB
    float* Lb1 = (float*)w2s;  // alias: used only before w2s is staged

    const int blk = blockIdx.x;
    const int b = blk >> 6, i = blk & 63;
    const int t = threadIdx.x;
    const int lane = t & 63;
    const int w = t >> 6;

    Lb1[t] = L[(b * 64 + i) * 256 + t] + gb1[t];
    __syncthreads();

    // build h1 tile (bf16, swizzled)
    const float2* R2 = (const float2*)(Rm + b * 64 * 256);
    for (int it = 0; it < 32; ++it) {
        int flat = it * 256 + t;      // 0..8191 = 64 rows * 128 col-pairs
        int j  = flat >> 7;
        int cp = flat & 127;
        float2 rv = R2[j * 128 + cp];
        float v0 = fmaxf(Lb1[2 * cp]     + rv.x, 0.f);
        float v1 = fmaxf(Lb1[2 * cp + 1] + rv.y, 0.f);
        unsigned pack = ((unsigned)f2bf(v1) << 16) | (unsigned)f2bf(v0);
        int byte = j * 512 + ((cp * 4) ^ ((j & 7) << 4));
        *(unsigned*)((char*)h1s + byte) = pack;
    }

    f32x4 acc[4][4];
    #pragma unroll
    for (int m = 0; m < 4; ++m)
        #pragma unroll
        for (int n = 0; n < 4; ++n)
            acc[m][n] = (f32x4){0.f, 0.f, 0.f, 0.f};

    for (int kc = 0; kc < 4; ++kc) {
        __syncthreads();   // h1 done (kc=0) / w2s readers done (kc>0)
        // stage W2T[:, kc*64 .. kc*64+64) into w2s, swizzled
        for (int it = 0; it < 8; ++it) {
            int flat = it * 256 + t;          // 0..2047 = 256 c * 8 slots
            int c = flat >> 3, s = flat & 7;
            short8 v = *(const short8*)(W2T + c * 256 + kc * 64 + s * 8);
            int byte = c * 128 + (((s ^ (c & 7)) << 4));
            *(short8*)((char*)w2s + byte) = v;
        }
        __syncthreads();
        #pragma unroll
        for (int ks = 0; ks < 2; ++ks) {
            int kk = kc * 64 + ks * 32 + ((lane >> 4) * 8);  // h1 k index
            int kl =           ks * 32 + ((lane >> 4) * 8);  // local k in chunk
            short8 a[4], bf[4];
            #pragma unroll
            for (int m = 0; m < 4; ++m) {
                int row = m * 16 + (lane & 15);
                int byte = row * 512 + ((2 * kk) ^ ((row & 7) << 4));
                a[m] = *(const short8*)((const char*)h1s + byte);
            }
            #pragma unroll
            for (int n = 0; n < 4; ++n) {
                int col = w * 64 + n * 16 + (lane & 15);
                int byte = col * 128 + ((2 * kl) ^ ((col & 7) << 4));
                bf[n] = *(const short8*)((const char*)w2s + byte);
            }
            #pragma unroll
            for (int m = 0; m < 4; ++m)
                #pragma unroll
                for (int n = 0; n < 4; ++n)
                    acc[m][n] = __builtin_amdgcn_mfma_f32_16x16x32_bf16(
                        a[m], bf[n], acc[m][n], 0, 0, 0);
        }
    }

    // epilogue: bias + relu + mask(j==i) + column sum
    #pragma unroll
    for (int n = 0; n < 4; ++n) {
        int col = w * 64 + n * 16 + (lane & 15);
        float bias = gb2[col];
        float colsum = 0.f;
        #pragma unroll
        for (int m = 0; m < 4; ++m) {
            #pragma unroll
            for (int q = 0; q < 4; ++q) {
                int row = m * 16 + ((lane >> 4) * 4) + q;  // == j
                float v = fmaxf(acc[m][n][q] + bias, 0.f);
                if (row == i) v = 0.f;
                colsum += v;
            }
        }
        colsum += __shfl_xor(colsum, 16);
        colsum += __shfl_xor(colsum, 32);
        if (lane < 16)
            atomicAdd(&S[b * 256 + col], colsum);
    }
}

// ---------------------------------------------------------------------------
// Final: per batch b: agg = S[b]@W3 + 4032*b3 ; out = relu(agg@fW1+fb1)@fW2+fb2
// ---------------------------------------------------------------------------
__global__ __launch_bounds__(256) void rn_final(
    const float* __restrict__ S, const float* __restrict__ gW3,
    const float* __restrict__ gb3, const float* __restrict__ fW1,
    const float* __restrict__ fb1, const float* __restrict__ fW2,
    const float* __restrict__ fb2, float* __restrict__ out)
{
    __shared__ float va[256];
    __shared__ float vb[256];
    const int b = blockIdx.x, t = threadIdx.x;

    va[t] = S[b * 256 + t];
    __syncthreads();
    float agg = 4032.0f * gb3[t];
    for (int k = 0; k < 256; ++k) agg += va[k] * gW3[k * 256 + t];
    vb[t] = agg;
    __syncthreads();
    float u = fb1[t];
    for (int k = 0; k < 256; ++k) u += vb[k] * fW1[k * 256 + t];
    u = fmaxf(u, 0.f);
    __syncthreads();
    va[t] = u;
    __syncthreads();
    float o = fb2[t];
    for (int k = 0; k < 256; ++k) o += va[k] * fW2[k * 256 + t];
    out[b * 256 + t] = o;
}

extern "C" void kernel_launch(void* const* d_in, const int* in_sizes, int n_in,
                              void* d_out, int out_size, void* d_ws, size_t ws_size,
                              hipStream_t stream)
{
    const float* obj = (const float*)d_in[0];
    const float* gW1 = (const float*)d_in[1];
    const float* gb1 = (const float*)d_in[2];
    const float* gW2 = (const float*)d_in[3];
    const float* gb2 = (const float*)d_in[4];
    const float* gW3 = (const float*)d_in[5];
    const float* gb3 = (const float*)d_in[6];
    const float* fW1 = (const float*)d_in[7];
    const float* fb1 = (const float*)d_in[8];
    const float* fW2 = (const float*)d_in[9];
    const float* fb2 = (const float*)d_in[10];
    float* out = (float*)d_out;

    char* ws = (char*)d_ws;
    float* L            = (float*)(ws);                              // 2 MB
    float* Rm           = (float*)(ws + (2u << 20));                 // 2 MB
    unsigned short* W2T = (unsigned short*)(ws + (4u << 20));        // 128 KB
    float* S            = (float*)(ws + (4u << 20) + (128u << 10));  // 32 KB

    rn_prep <<<145, 256, 0, stream>>>(obj, gW1, gW2, L, Rm, W2T, S);
    rn_main <<<BB * NN, 256, 0, stream>>>(L, Rm, W2T, gb1, gb2, S);
    rn_final<<<BB, 256, 0, stream>>>(S, gW3, gb3, fW1, fb1, fW2, fb2, out);
}